// Round 6
// baseline (146.282 us; speedup 1.0000x reference)
//
#include <hip/hip_runtime.h>
#include <math.h>

// x is (B=64, C=64, H=64, W=64) fp32, NCHW.
#define BDIM 64
#define CDIM 64
#define HWN  4096            // H*W
#define NROWS (BDIM * HWN)   // 262144 spatial rows
#define CHSTRIDE (CDIM * HWN)
#define EPSV 1e-5f

#define TILE 128                    // hw positions per block (per-row passes)
#define ROWBLOCKS (NROWS / TILE)    // 2048 blocks

// ws layout (floats), no atomics anywhere:
//  [0 .. 4095]        per-(b,c)-plane sums (plane = b*64 + c)   <- K1
//  [4096 .. 4159]     mu[64]                                    <- K_mu
//  [4224 .. 6271]     per-block d^2 partials (2048 blocks)      <- K2
//  [8192 .. +NROWS)   alpha per row                             <- K2
//  [COEF .. +NROWS)   coef per row                              <- K2
#define MU_OFF    4096
#define DD_OFF    4224
#define ALPHA_OFF 8192
#define COEF_OFF  (ALPHA_OFF + NROWS)

// ---------------- K1: per-plane sums (contiguous float4) ----------------
__global__ __launch_bounds__(256) void k_chansum(const float* __restrict__ x,
                                                 float* __restrict__ ws) {
    const int plane = blockIdx.x;          // b*C + c
    const float4* p4 = reinterpret_cast<const float4*>(x + (size_t)plane * HWN);
    float s = 0.f;
#pragma unroll
    for (int i = 0; i < HWN / 4 / 256; ++i) {
        float4 v = p4[threadIdx.x + i * 256];
        s += (v.x + v.y) + (v.z + v.w);
    }
    for (int off = 32; off; off >>= 1) s += __shfl_down(s, off, 64);
    __shared__ float red[4];
    const int lane = threadIdx.x & 63, wid = threadIdx.x >> 6;
    if (lane == 0) red[wid] = s;
    __syncthreads();
    if (threadIdx.x == 0) ws[plane] = (red[0] + red[1]) + (red[2] + red[3]);
}

// ---------------- K_mu: mu[64] once (1 block) ----------------
__global__ __launch_bounds__(256) void k_mu(float* __restrict__ ws) {
    __shared__ float stmp[256];
    const int t = threadIdx.x, c = t & 63, g = t >> 6;
    float m = 0.f;
#pragma unroll
    for (int b = 0; b < BDIM / 4; ++b) m += ws[(g * (BDIM / 4) + b) * CDIM + c];
    stmp[t] = m;
    __syncthreads();
    if (t < 64) {
        const float msum = (stmp[c] + stmp[64 + c]) + (stmp[128 + c] + stmp[192 + c]);
        const float mval = msum * (1.0f / (float)NROWS);
        float mm = (c == 0) ? mval * mval : -mval * mval;   // m0^2 - sum(m[1:]^2)
        for (int off = 32; off; off >>= 1) mm += __shfl_down(mm, off, 64);
        mm = __shfl(mm, 0, 64);
        ws[MU_OFF + c] = mval / sqrtf(fmaxf(mm, EPSV));
    }
}

// 2-wave block reduce (contains one __syncthreads)
__device__ __forceinline__ float block_reduce128(float v, float* red2) {
    for (int off = 32; off; off >>= 1) v += __shfl_down(v, off, 64);
    const int lane = threadIdx.x & 63, w = threadIdx.x >> 6;
    if (lane == 0) red2[w] = v;
    __syncthreads();
    return red2[0] + red2[1];
}

// Tile loader: 128 threads, [64][TILE] tile. Wave w, step s, lane-half h loads
// channel c=(w*16+s)*2+h as a 512 B contiguous segment (float4 per lane-half).
__device__ __forceinline__ void load_tile(const float* __restrict__ gbase,
                                          float* __restrict__ tile) {
    const int w = threadIdx.x >> 6, l = threadIdx.x & 63;
    const int h = l >> 5, j = l & 31;      // channel-half, float4 index
#pragma unroll
    for (int s = 0; s < 16; ++s) {
        const int c = (w * 16 + s) * 2 + h;
        const float4 v = *reinterpret_cast<const float4*>(gbase + (size_t)c * HWN + 4 * j);
        *reinterpret_cast<float4*>(&tile[c * TILE + 4 * j]) = v;
    }
}

// ---------------- K2: alpha/coef per row + d^2 partials ----------------
// 2048 blocks x 128 threads; thread t owns tile row t.
__global__ __launch_bounds__(128) void k_alpha(const float* __restrict__ x,
                                               float* __restrict__ ws) {
    __shared__ float tile[CDIM * TILE];    // 32 KB -> 4 blocks/CU
    __shared__ float smu[64], red2[2];
    if (threadIdx.x < 64) smu[threadIdx.x] = ws[MU_OFF + threadIdx.x];

    const int n0 = blockIdx.x * TILE;
    const int b = n0 >> 12;
    const int hw0 = n0 & (HWN - 1);
    load_tile(x + (size_t)b * CHSTRIDE + hw0, tile);
    __syncthreads();

    const int t = threadIdx.x;
    float a0 = tile[t] * smu[0]             - tile[TILE + t] * smu[1];
    float a1 = -tile[2 * TILE + t] * smu[2] - tile[3 * TILE + t] * smu[3];
    float a2 = 0.f, a3 = 0.f;
#pragma unroll
    for (int c = 4; c < CDIM; c += 4) {
        a0 -= tile[(c + 0) * TILE + t] * smu[c + 0];
        a1 -= tile[(c + 1) * TILE + t] * smu[c + 1];
        a2 -= tile[(c + 2) * TILE + t] * smu[c + 2];
        a3 -= tile[(c + 3) * TILE + t] * smu[c + 3];
    }
    float alpha = (a0 + a1) + (a2 + a3);
    alpha = fmaxf(alpha, 1.0f + EPSV);
    const float d = acoshf(alpha);
    const float coef = d / sqrtf(alpha * alpha - 1.0f);
    ws[ALPHA_OFF + n0 + t] = alpha;
    ws[COEF_OFF + n0 + t]  = coef;

    const float dd = block_reduce128(d * d, red2);
    if (t == 0) ws[DD_OFF + blockIdx.x] = dd;
}

// ---------------- K3: output transform (tile in, tile out) ----------------
// 2048 blocks x 128 threads.
__global__ __launch_bounds__(128) void k_out(const float* __restrict__ x,
                                             const float* __restrict__ gamma,
                                             const float* __restrict__ beta,
                                             float* __restrict__ out,
                                             const float* __restrict__ ws) {
    __shared__ float tile[CDIM * TILE];    // 32 KB -> 4 blocks/CU
    __shared__ float smu[64], sg[64], sb[64], red2[2];
    if (threadIdx.x < 64) {
        smu[threadIdx.x] = ws[MU_OFF + threadIdx.x];
        sg[threadIdx.x] = (threadIdx.x >= 1) ? gamma[threadIdx.x - 1] : 0.f;
        sb[threadIdx.x] = (threadIdx.x >= 1) ? beta[threadIdx.x - 1] : 0.f;
    }

    const int n0 = blockIdx.x * TILE;
    const int b = n0 >> 12;
    const int hw0 = n0 & (HWN - 1);
    const size_t gbase = (size_t)b * CHSTRIDE + hw0;
    load_tile(x + gbase, tile);            // loads in flight...

    // ...overlapped with the var re-reduce (2048 L2-hot partials, 16/thread);
    // block_reduce128's barrier also completes the tile.
    float pv = 0.f;
#pragma unroll
    for (int k = 0; k < ROWBLOCKS / TILE; ++k)
        pv += ws[DD_OFF + threadIdx.x + TILE * k];
    const float varsum = block_reduce128(pv, red2);
    const float var = varsum * (1.0f / (float)NROWS);
    const float inv_sv = 1.0f / (sqrtf(var) + EPSV);

    const int t = threadIdx.x;
    const float al = ws[ALPHA_OFF + n0 + t];
    const float co = ws[COEF_OFF + n0 + t];
    const float m0 = smu[0];
    const float kk = co * (tile[t] - al * m0) / (1.0f + m0);   // v0/(1+mu0)

    float s2 = 0.f;
#pragma unroll
    for (int c = 1; c < CDIM; ++c) {
        const float xv = tile[c * TILE + t];
        const float m = smu[c];
        const float v = co * (xv - al * m);
        const float vo = v - kk * m;             // mu_plus_o[c]==mu[c], c>=1
        const float s = (sg[c] * inv_sv) * vo + sb[c];
        s2 += s * s;
        tile[c * TILE + t] = s;                  // in-place, column-exclusive
    }
    tile[t] = sqrtf(1.0f + s2);                  // t channel (c=0)
    __syncthreads();

    // writeback: same mapping as load_tile, 512 B contiguous per lane-half
    const int w = t >> 6, l = t & 63;
    const int h = l >> 5, j = l & 31;
    float* obase = out + gbase;
#pragma unroll
    for (int s = 0; s < 16; ++s) {
        const int c = (w * 16 + s) * 2 + h;
        const float4 v = *reinterpret_cast<const float4*>(&tile[c * TILE + 4 * j]);
        *reinterpret_cast<float4*>(obase + (size_t)c * HWN + 4 * j) = v;
    }
}

extern "C" void kernel_launch(void* const* d_in, const int* in_sizes, int n_in,
                              void* d_out, int out_size, void* d_ws, size_t ws_size,
                              hipStream_t stream) {
    const float* x     = (const float*)d_in[0];
    const float* gamma = (const float*)d_in[1];
    const float* beta  = (const float*)d_in[2];
    float* out = (float*)d_out;
    float* ws  = (float*)d_ws;

    k_chansum<<<BDIM * CDIM, 256, 0, stream>>>(x, ws);
    k_mu<<<1, 256, 0, stream>>>(ws);
    k_alpha<<<ROWBLOCKS, 128, 0, stream>>>(x, ws);
    k_out<<<ROWBLOCKS, 128, 0, stream>>>(x, gamma, beta, out, ws);
}